// Round 7
// baseline (377.196 us; speedup 1.0000x reference)
//
#include <hip/hip_runtime.h>
#include <math.h>

#define NN 100000
#define NE 1600000
#define INF 128
#define HID 256
#define SCAN_BLK 256
#define NSCAN ((NN + SCAN_BLK - 1) / SCAN_BLK)   // 391
#define FGRP 8                    // dst-space partitions (≈ XCD count)
#define FRNG (NN / FGRP)          // 12500 nodes per group
#define EPB 2048                  // edges scanned per virtual block
#define NVB ((NE + EPB - 1) / EPB)

typedef short bf16x8 __attribute__((ext_vector_type(8)));
typedef float f32x4 __attribute__((ext_vector_type(4)));

__device__ __forceinline__ unsigned int f2bf(float f) {
    unsigned int u = __float_as_uint(f);
    u = u + 0x7FFFu + ((u >> 16) & 1u);   // RNE
    return u >> 16;
}

// ---- degree counting, XCD-partitioned by node range ----
// group g = blockIdx&7 owns nodes [g*FRNG,(g+1)*FRNG): its 50KB deg slices
// stay L2-resident on one XCD -> no 32B/atomic HBM writeback storm.
__global__ void k_count(const int* __restrict__ src, const int* __restrict__ dst,
                        int* __restrict__ deg_out, int* __restrict__ deg_in) {
    const int g = blockIdx.x & (FGRP - 1);
    const int vb = blockIdx.x >> 3;
    const int lo = g * FRNG, hiR = lo + FRNG;
    const int base = vb * EPB + threadIdx.x;
    #pragma unroll
    for (int k = 0; k < EPB / 256; ++k) {
        int e = base + k * 256;
        if (e < NE) {
            int s = src[e];
            if (s >= lo && s < hiR) atomicAdd(&deg_out[s], 1);
            int d = dst[e];
            if (d >= lo && d < hiR) atomicAdd(&deg_in[d], 1);
        }
    }
}

// ---- norms from int degrees ----
__global__ void k_norms(const int* __restrict__ deg_out, const int* __restrict__ deg_in,
                        float* __restrict__ nrm_out, float* __restrict__ nrm_in) {
    int i = blockIdx.x * blockDim.x + threadIdx.x;
    if (i < NN) {
        nrm_out[i] = rsqrtf(fmaxf((float)deg_out[i], 1.0f));
        nrm_in[i]  = rsqrtf(fmaxf((float)deg_in[i], 1.0f));
    }
}

// ---- xs = bf16(x * nrm_out[row]), packed 2/uint ----
__global__ void k_xconv(const float* __restrict__ x, const float* __restrict__ nrm_out,
                        unsigned int* __restrict__ xs) {
    int i = blockIdx.x * blockDim.x + threadIdx.x;   // one uint = 2 feats
    if (i >= NN * (INF / 2)) return;
    int row = i >> 6;                                 // 64 uints per row
    float n = nrm_out[row];
    float2 v = *reinterpret_cast<const float2*>(x + (size_t)i * 2);
    xs[i] = f2bf(v.x * n) | (f2bf(v.y * n) << 16);
}

// ---- W1 -> fragment-linear bf16 buffer + (b1,W2) pair table ----
// fragW[(nt*4+ks)*64 + l][i] = W1[ks*32 + (l>>4)*8 + i][nt*16 + (l&15)]
__global__ void k_wfrag(const float* __restrict__ W1, const float* __restrict__ b1,
                        const float* __restrict__ W2, unsigned short* __restrict__ fragW,
                        float2* __restrict__ bw) {
    int idx = blockIdx.x * blockDim.x + threadIdx.x;
    if (idx < 4096) {
        int l = idx & 63, ks = (idx >> 6) & 3, nt = idx >> 8;
        int kbase = ks * 32 + ((l >> 4) << 3);
        int col = nt * 16 + (l & 15);
        bf16x8 r;
        #pragma unroll
        for (int i = 0; i < 8; ++i)
            r[i] = (short)f2bf(W1[(size_t)(kbase + i) * HID + col]);
        *reinterpret_cast<bf16x8*>(fragW + (size_t)idx * 8) = r;
    } else if (idx < 4096 + HID) {
        int n = idx - 4096;
        bw[n] = make_float2(b1[n], W2[n]);
    }
}

// ---- scan phase 1: per-block sums of deg_in ----
__global__ void k_scan1(const int* __restrict__ deg_in, int* __restrict__ partial) {
    __shared__ int sh[SCAN_BLK];
    int i = blockIdx.x * SCAN_BLK + threadIdx.x;
    int v = (i < NN) ? deg_in[i] : 0;
    sh[threadIdx.x] = v;
    __syncthreads();
    for (int off = SCAN_BLK / 2; off > 0; off >>= 1) {
        if (threadIdx.x < off) sh[threadIdx.x] += sh[threadIdx.x + off];
        __syncthreads();
    }
    if (threadIdx.x == 0) partial[blockIdx.x] = sh[0];
}

// ---- scan phase 2: wave-parallel exclusive scan of 391 partials ----
__global__ void k_scan2(int* __restrict__ partial) {
    int lane = threadIdx.x;   // 64 threads, 1 block
    int carry = 0;
    for (int c = 0; c < NSCAN; c += 64) {
        int idx = c + lane;
        int v = (idx < NSCAN) ? partial[idx] : 0;
        int s = v;
        #pragma unroll
        for (int off = 1; off < 64; off <<= 1) {
            int t = __shfl_up(s, off, 64);
            if (lane >= off) s += t;
        }
        if (idx < NSCAN) partial[idx] = s - v + carry;
        carry += __shfl(s, 63, 64);
    }
}

// ---- scan phase 3: in-block exclusive scan + block offset -> offsets, cursor ----
__global__ void k_scan3(const int* __restrict__ deg_in, const int* __restrict__ partial,
                        int* __restrict__ offsets, int* __restrict__ cursor) {
    __shared__ int sh[SCAN_BLK];
    int i = blockIdx.x * SCAN_BLK + threadIdx.x;
    int v = (i < NN) ? deg_in[i] : 0;
    sh[threadIdx.x] = v;
    __syncthreads();
    for (int off = 1; off < SCAN_BLK; off <<= 1) {
        int t = (threadIdx.x >= off) ? sh[threadIdx.x - off] : 0;
        __syncthreads();
        sh[threadIdx.x] += t;
        __syncthreads();
    }
    int ex = sh[threadIdx.x] - v + partial[blockIdx.x];
    if (i < NN) {
        offsets[i] = ex;
        cursor[i] = ex;
    }
    if (i == 0) offsets[NN] = NE;
}

// ---- CSR fill, XCD-partitioned by dst range ----
__global__ void k_fill(const int* __restrict__ src, const int* __restrict__ dst,
                       int* __restrict__ cursor, int* __restrict__ csr_src) {
    const int g = blockIdx.x & (FGRP - 1);
    const int vb = blockIdx.x >> 3;
    const int lo = g * FRNG, hiR = lo + FRNG;
    const int base = vb * EPB + threadIdx.x;
    #pragma unroll
    for (int k = 0; k < EPB / 256; ++k) {
        int e = base + k * 256;
        if (e < NE) {
            int d = dst[e];
            if (d >= lo && d < hiR) {
                int p = atomicAdd(&cursor[d], 1);
                csr_src[p] = src[e];
            }
        }
    }
}

// ---- gather: aggb[v] = bf16( nrm_in[v] * sum xs[src] ), one wave per row ----
__global__ void k_gather(const unsigned int* __restrict__ xs, const int* __restrict__ offsets,
                         const int* __restrict__ csr_src, const float* __restrict__ nrm_in,
                         unsigned int* __restrict__ aggb) {
    int row = blockIdx.x * 4 + (threadIdx.x >> 6);   // 4 waves/block
    if (row >= NN) return;
    int lane = threadIdx.x & 63;
    int beg = offsets[row], end = offsets[row + 1];
    float a0 = 0.f, a1 = 0.f, b0 = 0.f, b1 = 0.f;
    int j = beg;
    for (; j + 1 < end; j += 2) {
        unsigned int p0 = xs[(size_t)csr_src[j] * 64 + lane];
        unsigned int p1 = xs[(size_t)csr_src[j + 1] * 64 + lane];
        a0 += __uint_as_float(p0 << 16);
        a1 += __uint_as_float(p0 & 0xFFFF0000u);
        b0 += __uint_as_float(p1 << 16);
        b1 += __uint_as_float(p1 & 0xFFFF0000u);
    }
    if (j < end) {
        unsigned int p0 = xs[(size_t)csr_src[j] * 64 + lane];
        a0 += __uint_as_float(p0 << 16);
        a1 += __uint_as_float(p0 & 0xFFFF0000u);
    }
    float ni = nrm_in[row];
    float lo = (a0 + b0) * ni, hi = (a1 + b1) * ni;
    aggb[(size_t)row * 64 + lane] = f2bf(lo) | (f2bf(hi) << 16);
}

// ---- MFMA GEMM (no LDS) + relu + W2-dot + shfl-reduce -> z ----
__launch_bounds__(256)
__global__ void k_gemm(const unsigned short* __restrict__ aggb,
                       const unsigned short* __restrict__ fragW,
                       const float2* __restrict__ bw, const float* __restrict__ nrm_out,
                       float* __restrict__ z) {
    const int l = threadIdx.x & 63;
    const int w = threadIdx.x >> 6;
    const int r0 = blockIdx.x * 64 + w * 16;
    const int n15 = l & 15;
    const int hi = l >> 4;
    const int arow = r0 + n15;

    bf16x8 a[4];
    if (arow < NN) {
        #pragma unroll
        for (int ks = 0; ks < 4; ++ks)
            a[ks] = *reinterpret_cast<const bf16x8*>(aggb + (size_t)arow * INF + ks * 32 + (hi << 3));
    } else {
        #pragma unroll
        for (int ks = 0; ks < 4; ++ks) a[ks] = (bf16x8){0, 0, 0, 0, 0, 0, 0, 0};
    }

    float pacc[4] = {0.f, 0.f, 0.f, 0.f};
    #pragma unroll
    for (int nt = 0; nt < 16; ++nt) {
        f32x4 acc = {0.f, 0.f, 0.f, 0.f};
        #pragma unroll
        for (int ks = 0; ks < 4; ++ks) {
            bf16x8 b = *reinterpret_cast<const bf16x8*>(fragW + (size_t)(((nt * 4 + ks) * 64 + l) << 3));
            acc = __builtin_amdgcn_mfma_f32_16x16x32_bf16(a[ks], b, acc, 0, 0, 0);
        }
        float2 c = bw[nt * 16 + n15];
        #pragma unroll
        for (int g = 0; g < 4; ++g)
            pacc[g] += fmaxf(acc[g] + c.x, 0.f) * c.y;
    }
    #pragma unroll
    for (int off = 1; off < 16; off <<= 1) {
        #pragma unroll
        for (int g = 0; g < 4; ++g) pacc[g] += __shfl_xor(pacc[g], off, 64);
    }
    if (n15 == 0) {
        #pragma unroll
        for (int g = 0; g < 4; ++g) {
            int gr = r0 + (hi << 2) + g;
            if (gr < NN) z[gr] = nrm_out[gr] * pacc[g];
        }
    }
}

// ---- layer-2 gather + sigmoid: 16 lanes per node, shfl reduce ----
__global__ void k_out(const float* __restrict__ z, const int* __restrict__ offsets,
                      const int* __restrict__ csr_src, const float* __restrict__ nrm_in,
                      const float* __restrict__ b2, float* __restrict__ out) {
    int v = blockIdx.x * 16 + (threadIdx.x >> 4);
    if (v >= NN) return;
    int li = threadIdx.x & 15;
    int beg = offsets[v], end = offsets[v + 1];
    float s = 0.f;
    for (int j = beg + li; j < end; j += 16) s += z[csr_src[j]];
    #pragma unroll
    for (int off = 1; off < 16; off <<= 1) s += __shfl_xor(s, off, 64);
    if (li == 0) {
        float val = s * nrm_in[v] + b2[0];
        out[v] = 1.0f / (1.0f + expf(-val));
    }
}

extern "C" void kernel_launch(void* const* d_in, const int* in_sizes, int n_in,
                              void* d_out, int out_size, void* d_ws, size_t ws_size,
                              hipStream_t stream) {
    const float* x   = (const float*)d_in[0];
    const int*   src = (const int*)d_in[1];
    const int*   dst = (const int*)d_in[2];
    const float* W1  = (const float*)d_in[3];
    const float* b1  = (const float*)d_in[4];
    const float* W2  = (const float*)d_in[5];
    const float* b2  = (const float*)d_in[6];
    float* out = (float*)d_out;

    // workspace layout (cursor aliases deg_out; deg_out consumed by k_norms
    // before k_scan3 overwrites the region as cursor)
    int*   deg_out = (int*)d_ws;                     // NN
    int*   deg_in  = deg_out + NN;                   // NN
    int*   offsets = deg_in + NN;                    // NN+1
    int*   partial = offsets + NN + 1;               // NSCAN
    int*   csr_src = partial + NSCAN;                // NE
    float* nrm_out = (float*)(csr_src + NE);         // NN
    float* nrm_in  = nrm_out + NN;                   // NN
    float* z       = nrm_in + NN;                    // NN
    float2* bw     = (float2*)(z + NN);              // HID
    unsigned int* xs   = (unsigned int*)(bw + HID);  // NN*64  (25.6 MB)
    unsigned int* aggb = xs + (size_t)NN * 64;       // NN*64  (25.6 MB)
    unsigned short* fragW = (unsigned short*)(aggb + (size_t)NN * 64);  // 64 KB
    int* cursor = deg_out;

    (void)hipMemsetAsync(deg_out, 0, 2 * NN * sizeof(int), stream);

    k_wfrag<<<17, 256, 0, stream>>>(W1, b1, W2, fragW, bw);
    k_count<<<NVB * FGRP, 256, 0, stream>>>(src, dst, deg_out, deg_in);
    k_norms<<<(NN + 255) / 256, 256, 0, stream>>>(deg_out, deg_in, nrm_out, nrm_in);
    k_xconv<<<(NN * 64 + 255) / 256, 256, 0, stream>>>(x, nrm_out, xs);
    k_scan1<<<NSCAN, SCAN_BLK, 0, stream>>>(deg_in, partial);
    k_scan2<<<1, 64, 0, stream>>>(partial);
    k_scan3<<<NSCAN, SCAN_BLK, 0, stream>>>(deg_in, partial, offsets, cursor);
    k_fill<<<NVB * FGRP, 256, 0, stream>>>(src, dst, cursor, csr_src);
    k_gather<<<NN / 4, 256, 0, stream>>>(xs, offsets, csr_src, nrm_in, aggb);
    k_gemm<<<(NN + 63) / 64, 256, 0, stream>>>((const unsigned short*)aggb, fragW, bw, nrm_out, z);
    k_out<<<(NN + 15) / 16, 256, 0, stream>>>(z, offsets, csr_src, nrm_in, b2, out);
}